// Round 4
// baseline (164.461 us; speedup 1.0000x reference)
//
#include <hip/hip_runtime.h>
#include <hip/hip_bf16.h>

#define B_  16
#define N_  16
#define H_  640
#define W_  640
#define HP_ 300
#define WP_ 300
#define IMG_FLOATS (H_ * W_ * 3)              // 1,228,800
#define ALL_FLOATS (B_ * IMG_FLOATS)          // 19,660,800
#define PBOX_OFF   ALL_FLOATS
#define IMG_F4     (IMG_FLOATS / 4)           // 307,200
#define F4_PER_BLOCK 768
#define BLOCKS_PER_IMG (IMG_F4 / F4_PER_BLOCK)   // 400
#define CELLS_PER_IMG (H_ * W_ / 64)          // 6400 (640%64==0 -> cell = pixel>>6)
#define CM_OFF_BYTES (B_ * N_ * 4 * 4)        // info: 256 entries x 4 ints = 4096 B

// d_ws layout: [0,4096): boxinfo (y0,x0,s,flags) x 256
//              [4096, 4096+204800): cell mask table uint16 [B][6400]

__global__ __launch_bounds__(256) void prep_kernel(
    const float* __restrict__ boxes,           // [B,N,4]
    const unsigned char* __restrict__ dec_raw, // [B,N,3] bool/int32/float32 (detected)
    float* __restrict__ pboxes_out,            // [B,N,4] -> d_out tail
    int* __restrict__ info,                    // 256*4 ints
    unsigned short* __restrict__ cm,           // [B][6400]
    int build_cm)
{
    int b = blockIdx.x;           // one block per image
    int t = threadIdx.x;
    __shared__ int s_nz, s_fp;
    __shared__ int ly0[N_], lx0[N_], ls[N_], lfl[N_];
    if (t == 0) { s_nz = 0; s_fp = 0; }
    __syncthreads();
    int nz = 0, fp = 0;
    for (int i = t; i < B_ * N_ * 3; i += 256) {   // first 768 bytes valid under all layouts
        unsigned char by = dec_raw[i];
        if ((i & 3) && by) nz = 1;
        if (by == 0x3F || by == 0x80) fp = 1;
    }
    if (nz) atomicOr(&s_nz, 1);
    if (fp) atomicOr(&s_fp, 1);
    __syncthreads();
    int mode = !s_nz ? 1 : (s_fp ? 2 : 0);   // 0=bool8, 1=int32, 2=float32

    if (t < N_) {
        int e = b * N_ + t;
        float ymin = boxes[e*4+0], xmin = boxes[e*4+1];
        float h = boxes[e*4+2], w = boxes[e*4+3];
        float ph = h * 0.2f;
        float pw = 1.0f * ph;                 // ASPECT=1
        float y0 = ymin + h * 0.5f;
        float x0 = xmin + w * 0.5f;
        if (y0 + ph > (float)H_) y0 = (float)H_ - ph;
        if (x0 + pw > (float)W_) x0 = (float)W_ - pw;
        pboxes_out[e*4+0] = y0; pboxes_out[e*4+1] = x0;
        pboxes_out[e*4+2] = ph; pboxes_out[e*4+3] = pw;

        int y0i = (int)y0, x0i = (int)x0;     // tf.cast truncation
        int phi = (int)ph, pwi = (int)pw;
        int valid = (phi * pwi) > 400;        // AREA_THRESH
        int s = phi > 1 ? phi : 1;

        int d0, d1, d2;
        if (mode == 0) {
            d0 = dec_raw[e*3+0] != 0; d1 = dec_raw[e*3+1] != 0; d2 = dec_raw[e*3+2] != 0;
        } else if (mode == 1) {
            const int* di = (const int*)dec_raw;
            d0 = di[e*3+0] != 0; d1 = di[e*3+1] != 0; d2 = di[e*3+2] != 0;
        } else {
            const float* df = (const float*)dec_raw;
            d0 = df[e*3+0] != 0.0f; d1 = df[e*3+1] != 0.0f; d2 = df[e*3+2] != 0.0f;
        }
        int flags = valid | (d0 << 1) | (d1 << 2) | (d2 << 3);
        ly0[t] = y0i; lx0[t] = x0i; ls[t] = s; lfl[t] = flags;
        int* ei = info + e * 4;
        ei[0] = y0i; ei[1] = x0i; ei[2] = s; ei[3] = flags;
    }
    __syncthreads();

    if (build_cm) {
        unsigned short* cmb = cm + b * CELLS_PER_IMG;
        for (int c = t; c < CELLS_PER_IMG; c += 256) {
            int gy  = c / (W_ / 64);                 // 10 cells per row
            int gx0 = (c - gy * (W_ / 64)) * 64;
            unsigned m16 = 0;
            for (int m = 0; m < N_; ++m) {
                if ((lfl[m] & 1) &&
                    (unsigned)(gy - ly0[m]) < (unsigned)ls[m] &&
                    lx0[m] < gx0 + 64 && lx0[m] + ls[m] > gx0)
                    m16 |= 1u << m;
            }
            cmb[c] = (unsigned short)m16;
        }
    }
}

__device__ __forceinline__ int sample_px(
    int p, unsigned mask,
    const int* ly0, const int* lx0, const int* ls, const int* lfl,
    const float* __restrict__ patch,
    float& cr, float& cg, float& cb)
{
    int gy = p / W_;
    int gx = p - gy * W_;
    while (mask) {
        int m = 31 - __clz(mask);            // highest index = last write wins
        int s = ls[m];
        int ry = gy - ly0[m], rx = gx - lx0[m];
        if ((unsigned)ry < (unsigned)s && (unsigned)rx < (unsigned)s) {
            int fl = lfl[m];
            // invert transforms: flip_ud, flip_lr, then rot90 (CCW)
            int iy2 = (fl & 8) ? (s - 1 - ry) : ry;
            int ix2 = (fl & 4) ? (s - 1 - rx) : rx;
            int ty  = (fl & 2) ? ix2 : iy2;
            int tx  = (fl & 2) ? (s - 1 - iy2) : ix2;
            float sf  = (float)s;
            float sc  = (float)HP_ / sf;
            float sy = ((float)ty + 0.5f) * sc - 0.5f;
            float sx = ((float)tx + 0.5f) * sc - 0.5f;
            sy = fminf(fmaxf(sy, 0.0f), (float)(HP_ - 1));
            sx = fminf(fmaxf(sx, 0.0f), (float)(WP_ - 1));
            int yy0 = (int)sy;               // sy >= 0 -> trunc == floor
            int xx0 = (int)sx;
            int yy1 = yy0 + 1 < HP_ - 1 ? yy0 + 1 : HP_ - 1;
            int xx1 = xx0 + 1 < WP_ - 1 ? xx0 + 1 : WP_ - 1;
            float wy = sy - (float)yy0;
            float wx = sx - (float)xx0;
            const float* p00 = patch + (yy0 * WP_ + xx0) * 3;
            const float* p01 = patch + (yy0 * WP_ + xx1) * 3;
            const float* p10 = patch + (yy1 * WP_ + xx0) * 3;
            const float* p11 = patch + (yy1 * WP_ + xx1) * 3;
            float t0 = p00[0]*(1.f-wx) + p01[0]*wx;
            float b0 = p10[0]*(1.f-wx) + p11[0]*wx;
            cr = t0*(1.f-wy) + b0*wy;
            float t1 = p00[1]*(1.f-wx) + p01[1]*wx;
            float b1 = p10[1]*(1.f-wx) + p11[1]*wx;
            cg = t1*(1.f-wy) + b1*wy;
            float t2 = p00[2]*(1.f-wx) + p01[2]*wx;
            float b2 = p10[2]*(1.f-wx) + p11[2]*wx;
            cb = t2*(1.f-wy) + b2*wy;
            return 1;
        }
        mask &= ~(1u << m);
    }
    return 0;
}

__device__ __forceinline__ float4 process_f4(
    float4 v, int f,       // f = float4 index within the image
    const unsigned short* __restrict__ cmb,
    const int* ly0, const int* lx0, const int* ls, const int* lfl,
    const float* __restrict__ patch, int use_tab)
{
    // wave-uniform chunk mask (64 consecutive float4s -> <=3 consecutive 64px cells)
    int wlo = f & ~63;
    int whi = wlo + 63;
    int px_lo = wlo + wlo / 3;               // (4*wlo)/3
    int px_hi = (4 * whi + 3) / 3;
    unsigned mask;
    if (use_tab) {
        int c0 = px_lo >> 6, c1 = px_hi >> 6;
        mask = (unsigned)cmb[c0] | (unsigned)cmb[c1];
        if (c1 == c0 + 2) mask |= (unsigned)cmb[c0 + 1];
    } else {
        int ry0 = px_lo / W_, ry1 = px_hi / W_;
        int cx0, cx1;
        if (ry0 == ry1) { cx0 = px_lo - ry0 * W_; cx1 = px_hi - ry0 * W_; }
        else            { cx0 = 0; cx1 = W_ - 1; }
        mask = 0;
        for (int m = 0; m < N_; ++m)
            if ((lfl[m] & 1) && ly0[m] <= ry1 && ly0[m] + ls[m] > ry0 &&
                lx0[m] <= cx1 && lx0[m] + ls[m] > cx0)
                mask |= 1u << m;
    }
    if (!mask) return v;                     // fast path: pure copy

    int p0 = f + f / 3;                      // (4f)/3; floats 4f..4f+3 span pixels p0,p0+1
    float c00, c01, c02, c10, c11, c12;
    int h0 = sample_px(p0,     mask, ly0, lx0, ls, lfl, patch, c00, c01, c02);
    int h1 = sample_px(p0 + 1, mask, ly0, lx0, ls, lfl, patch, c10, c11, c12);
    if (!(h0 | h1)) return v;

    int r = f % 3;                           // (4f)%3 pattern selector -> all-static indexing
    float vv0 = v.x, vv1 = v.y, vv2 = v.z, vv3 = v.w;
    if (r == 0) {
        if (h0) { vv0 = c00; vv1 = c01; vv2 = c02; }
        if (h1) { vv3 = c10; }
    } else if (r == 1) {
        if (h0) { vv0 = c01; vv1 = c02; }
        if (h1) { vv2 = c10; vv3 = c11; }
    } else {
        if (h0) { vv0 = c02; }
        if (h1) { vv1 = c10; vv2 = c11; vv3 = c12; }
    }
    return make_float4(vv0, vv1, vv2, vv3);
}

__global__ __launch_bounds__(256) void fused_kernel(
    const float4* __restrict__ images4,
    const float*  __restrict__ patch,
    const int*    __restrict__ info,
    const unsigned short* __restrict__ cm,
    float4*       __restrict__ out4,
    int use_tab)
{
    int blk = blockIdx.x;
    int b = blk / BLOCKS_PER_IMG;
    int blkLocal = blk - b * BLOCKS_PER_IMG;
    int t = threadIdx.x;

    __shared__ int ly0[N_], lx0[N_], ls[N_], lfl[N_];
    if (t < N_) {
        const int* ei = info + (b * N_ + t) * 4;
        ly0[t] = ei[0]; lx0[t] = ei[1]; ls[t] = ei[2]; lfl[t] = ei[3];
    }
    __syncthreads();

    const float4* ib = images4 + (size_t)b * IMG_F4;
    float4*       ob = out4    + (size_t)b * IMG_F4;
    const unsigned short* cmb = cm + b * CELLS_PER_IMG;

    int f0 = blkLocal * F4_PER_BLOCK + t;    // lane-contiguous, fully coalesced
    float4 v0 = ib[f0];
    float4 v1 = ib[f0 + 256];
    float4 v2 = ib[f0 + 512];

    v0 = process_f4(v0, f0,       cmb, ly0, lx0, ls, lfl, patch, use_tab);
    v1 = process_f4(v1, f0 + 256, cmb, ly0, lx0, ls, lfl, patch, use_tab);
    v2 = process_f4(v2, f0 + 512, cmb, ly0, lx0, ls, lfl, patch, use_tab);

    ob[f0]       = v0;
    ob[f0 + 256] = v1;
    ob[f0 + 512] = v2;
}

extern "C" void kernel_launch(void* const* d_in, const int* in_sizes, int n_in,
                              void* d_out, int out_size, void* d_ws, size_t ws_size,
                              hipStream_t stream) {
    const float*         boxes   = (const float*)d_in[0];
    const float*         images  = (const float*)d_in[1];
    const float*         patch   = (const float*)d_in[2];
    const unsigned char* dec_raw = (const unsigned char*)d_in[3];

    float* out    = (float*)d_out;
    float* pboxes = out + PBOX_OFF;
    int*   info   = (int*)d_ws;
    unsigned short* cm = (unsigned short*)((char*)d_ws + CM_OFF_BYTES);
    size_t need = CM_OFF_BYTES + (size_t)B_ * CELLS_PER_IMG * sizeof(unsigned short);
    int use_tab = (ws_size >= need) ? 1 : 0;

    prep_kernel<<<B_, 256, 0, stream>>>(boxes, dec_raw, pboxes, info, cm, use_tab);
    fused_kernel<<<B_ * BLOCKS_PER_IMG, 256, 0, stream>>>(
        (const float4*)images, patch, info, cm, (float4*)out, use_tab);
}